// Round 1
// baseline (493.633 us; speedup 1.0000x reference)
//
#include <hip/hip_runtime.h>
#include <math.h>

// Problem constants (B,N,K,D,V,L) = (16,512,16,256,64,2)
#define Bc 16
#define Nn 512
#define Kn 16
#define Dd 256
#define NC 1024          // 4*D
#define MR 8192          // B*N

// ---------------------------------------------------------------------------
// Build folded, gate-permuted weights.
//   X columns: [0,256)=Nh_in  [256,512)=Nh_out  [512,768)=E_in  [768,1024)=E_out
//   W0 (1024x1024): rows [Wi_top; Wo_top; Wi_bot+Ui_bot; Wo_bot+Uo_bot]
//   Wl (512x1024) : rows [Ui_top; Uo_top]
//   Column permutation: c' = 4*d+g  <->  c = g*256+d   (g=gate, d=output dim)
//   bias = bi+bo+bui+buo (permuted)
// ---------------------------------------------------------------------------
__global__ void prep_weights_kernel(const float* __restrict__ Wi, const float* __restrict__ Wo,
                                    const float* __restrict__ Ui, const float* __restrict__ Uo,
                                    const float* __restrict__ bi, const float* __restrict__ bo,
                                    const float* __restrict__ bui, const float* __restrict__ buo,
                                    float* __restrict__ W0, float* __restrict__ Wl,
                                    float* __restrict__ bias) {
  const int total = 1024 * 1024 + 512 * 1024 + 1024;
  for (int idx = blockIdx.x * blockDim.x + threadIdx.x; idx < total;
       idx += gridDim.x * blockDim.x) {
    if (idx < 1024 * 1024) {
      int r = idx >> 10, cp = idx & 1023;
      int d = cp >> 2, g = cp & 3;
      int c = g * 256 + d;
      float v;
      if (r < 256)       v = Wi[r * NC + c];
      else if (r < 512)  v = Wo[(r - 256) * NC + c];
      else if (r < 768)  v = Wi[(r - 256) * NC + c] + Ui[(r - 256) * NC + c];
      else               v = Wo[(r - 512) * NC + c] + Uo[(r - 512) * NC + c];
      W0[idx] = v;
    } else if (idx < 1024 * 1024 + 512 * 1024) {
      int j = idx - 1024 * 1024;
      int r = j >> 10, cp = j & 1023;
      int d = cp >> 2, g = cp & 3;
      int c = g * 256 + d;
      Wl[j] = (r < 256) ? Ui[r * NC + c] : Uo[(r - 256) * NC + c];
    } else {
      int cp = idx - (1024 * 1024 + 512 * 1024);
      int d = cp >> 2, g = cp & 3;
      int c = g * 256 + d;
      bias[cp] = bi[c] + bo[c] + bui[c] + buo[c];
    }
  }
}

// ---------------------------------------------------------------------------
// Aggregation: one block per (b,n) row, 256 threads over d.
//   Nh_in[d]  = sum_k in_mask * h[b, in_idx[k], d]   -> X[row][d]
//   Nh_out[d] = sum_k out_mask* h[b, out_idx[k], d]  -> X[row][256+d]
//   (EDGES) E_in/E_out similarly from edge_emb       -> X[row][512+d / 768+d]
// ---------------------------------------------------------------------------
template <bool EDGES>
__global__ __launch_bounds__(256) void agg_kernel(
    const float* __restrict__ h,
    const int* __restrict__ in_idx, const float* __restrict__ in_m,
    const int* __restrict__ out_idx, const float* __restrict__ out_m,
    const int* __restrict__ in_e, const int* __restrict__ out_e,
    const float* __restrict__ edge_emb,
    float* __restrict__ X) {
  const int row = blockIdx.x;       // b*N+n
  const int d = threadIdx.x;        // 0..255
  const int base = row * Kn;
  const int hbase = (row >> 9) << 9;  // b*N

  __shared__ int s_ii[Kn], s_oi[Kn], s_ie[Kn], s_oe[Kn];
  __shared__ float s_im[Kn], s_om[Kn];
  if (threadIdx.x < Kn) {
    s_ii[threadIdx.x] = in_idx[base + threadIdx.x];
    s_oi[threadIdx.x] = out_idx[base + threadIdx.x];
    s_im[threadIdx.x] = in_m[base + threadIdx.x];
    s_om[threadIdx.x] = out_m[base + threadIdx.x];
    if (EDGES) {
      s_ie[threadIdx.x] = in_e[base + threadIdx.x];
      s_oe[threadIdx.x] = out_e[base + threadIdx.x];
    }
  }
  __syncthreads();

  float accNi = 0.f, accNo = 0.f, accEi = 0.f, accEo = 0.f;
#pragma unroll
  for (int k = 0; k < Kn; k++) {
    accNi += s_im[k] * h[(size_t)(hbase + s_ii[k]) * Dd + d];
    accNo += s_om[k] * h[(size_t)(hbase + s_oi[k]) * Dd + d];
    if (EDGES) {
      accEi += s_im[k] * edge_emb[(size_t)s_ie[k] * Dd + d];
      accEo += s_om[k] * edge_emb[(size_t)s_oe[k] * Dd + d];
    }
  }
  float* xr = X + (size_t)row * NC;
  xr[d] = accNi;
  xr[256 + d] = accNo;
  if (EDGES) {
    xr[512 + d] = accEi;
    xr[768 + d] = accEo;
  }
}

// ---------------------------------------------------------------------------
// fp32 tiled GEMM: C = A(M x KDIM, lda=1024) @ W(KDIM x 1024)
//   MODE 0: out0 = C + bias                       (z_base)
//   MODE 1: fused LSTM epilogue. z = C + zbase; gate quad at cols 4d..4d+3
//           (ig,fg,og,ci); c_new = fg*c + ig*ci; h = og*tanh(c_new);
//           write c_new*mask -> cbuf, h*mask -> hbuf and out0 (reps slot).
//   FIRST: treat c as 0 (no read).
// Tile 128x128, BK=16, 256 threads, 8x8 micro-tile per thread.
// ---------------------------------------------------------------------------
#define BM 128
#define BN 128
#define BK 16

template <int KDIM, int MODE, bool FIRST>
__global__ __launch_bounds__(256) void gemm_kernel(
    const float* __restrict__ A, const float* __restrict__ W,
    const float* __restrict__ bias, const float* __restrict__ zbase,
    const float* __restrict__ mask,
    float* __restrict__ out0, float* __restrict__ hbuf, float* __restrict__ cbuf) {
  __shared__ float As[BK][BM + 4];
  __shared__ float Bs[BK][BN + 4];

  const int bx = blockIdx.x & 7;    // NC/BN = 8
  const int by = blockIdx.x >> 3;   // MR/BM = 64
  const int tid = threadIdx.x;
  const int tx = tid & 15, ty = tid >> 4;

  float acc[8][8] = {};

  const float* Aq = A + (size_t)(by * BM) * NC;
  const float* Wq = W + bx * BN;

  for (int k0 = 0; k0 < KDIM; k0 += BK) {
#pragma unroll
    for (int p = 0; p < 2; p++) {
      int i = tid + p * 256;
      // A tile: 128 rows x 16 cols (transposed into As)
      int r = i >> 2, c4 = i & 3;
      float4 va = *(const float4*)(Aq + (size_t)r * NC + k0 + c4 * 4);
      As[c4 * 4 + 0][r] = va.x;
      As[c4 * 4 + 1][r] = va.y;
      As[c4 * 4 + 2][r] = va.z;
      As[c4 * 4 + 3][r] = va.w;
      // W tile: 16 rows x 128 cols
      int rb = i >> 5, cb4 = i & 31;
      float4 vw = *(const float4*)(Wq + (size_t)(k0 + rb) * NC + cb4 * 4);
      *(float4*)&Bs[rb][cb4 * 4] = vw;
    }
    __syncthreads();
#pragma unroll
    for (int k = 0; k < BK; k++) {
      float a[8], b[8];
      *(float4*)&a[0] = *(const float4*)&As[k][ty * 8];
      *(float4*)&a[4] = *(const float4*)&As[k][ty * 8 + 4];
      *(float4*)&b[0] = *(const float4*)&Bs[k][tx * 8];
      *(float4*)&b[4] = *(const float4*)&Bs[k][tx * 8 + 4];
#pragma unroll
      for (int ii = 0; ii < 8; ii++)
#pragma unroll
        for (int jj = 0; jj < 8; jj++) acc[ii][jj] += a[ii] * b[jj];
    }
    __syncthreads();
  }

  const int row0 = by * BM + ty * 8;
  const int col0 = bx * BN + tx * 8;

  if (MODE == 0) {
    float bb[8];
#pragma unroll
    for (int j = 0; j < 8; j++) bb[j] = bias[col0 + j];
#pragma unroll
    for (int i = 0; i < 8; i++) {
      float o[8];
#pragma unroll
      for (int j = 0; j < 8; j++) o[j] = acc[i][j] + bb[j];
      float* dst = out0 + (size_t)(row0 + i) * NC + col0;
      *(float4*)dst = *(float4*)&o[0];
      *(float4*)(dst + 4) = *(float4*)&o[4];
    }
  } else {
    const int d0 = col0 >> 2;  // first output dim of this thread's 8 cols
#pragma unroll
    for (int i = 0; i < 8; i++) {
      const int row = row0 + i;
      const float mk = mask[row];
      const float* zb = zbase + (size_t)row * NC + col0;
      float z[8];
      *(float4*)&z[0] = *(const float4*)&zb[0];
      *(float4*)&z[4] = *(const float4*)&zb[4];
#pragma unroll
      for (int q = 0; q < 2; q++) {
        float zi = acc[i][q * 4 + 0] + z[q * 4 + 0];
        float zf = acc[i][q * 4 + 1] + z[q * 4 + 1];
        float zo = acc[i][q * 4 + 2] + z[q * 4 + 2];
        float zc = acc[i][q * 4 + 3] + z[q * 4 + 3];
        float ig = 1.f / (1.f + expf(-zi));
        float fg = 1.f / (1.f + expf(-zf));
        float og = 1.f / (1.f + expf(-zo));
        float ci = tanhf(zc);
        size_t off = (size_t)row * Dd + (d0 + q);
        float cold = FIRST ? 0.f : cbuf[off];
        float cn = fg * cold + ig * ci;
        float hn = og * tanhf(cn);
        cbuf[off] = cn * mk;
        float hm = hn * mk;
        hbuf[off] = hm;
        out0[off] = hm;  // reps slot for this iteration
      }
    }
  }
}

// ---------------------------------------------------------------------------
extern "C" void kernel_launch(void* const* d_in, const int* in_sizes, int n_in,
                              void* d_out, int out_size, void* d_ws, size_t ws_size,
                              hipStream_t stream) {
  const float* node_reps = (const float*)d_in[0];
  const float* mask      = (const float*)d_in[1];
  const int*   in_idx    = (const int*)d_in[2];
  const int*   in_edges  = (const int*)d_in[3];
  const float* in_mask   = (const float*)d_in[4];
  const int*   out_idx   = (const int*)d_in[5];
  const int*   out_edges = (const int*)d_in[6];
  const float* out_mask  = (const float*)d_in[7];
  const float* edge_emb  = (const float*)d_in[8];
  const float* Wi  = (const float*)d_in[9];
  const float* Wo  = (const float*)d_in[10];
  const float* Ui  = (const float*)d_in[11];
  const float* Uo  = (const float*)d_in[12];
  const float* bi  = (const float*)d_in[13];
  const float* bo  = (const float*)d_in[14];
  const float* bui = (const float*)d_in[15];
  const float* buo = (const float*)d_in[16];

  float* out   = (float*)d_out;
  const size_t MD = (size_t)MR * Dd;  // 2,097,152
  float* reps0 = out;
  float* reps1 = out + MD;
  float* hbuf  = out + 2 * MD;  // final h chunk doubles as working h
  float* cbuf  = out + 3 * MD;  // final c chunk doubles as working c

  float* ws    = (float*)d_ws;
  float* X     = ws;                          // MR*NC (32 MB)
  float* zbase = X + (size_t)MR * NC;         // MR*NC (32 MB)
  float* W0    = zbase + (size_t)MR * NC;     // 1024*1024 (4 MB)
  float* Wl    = W0 + 1024 * 1024;            // 512*1024 (2 MB)
  float* bias  = Wl + 512 * 1024;             // 1024

  // 1. fold + permute weights
  prep_weights_kernel<<<256, 256, 0, stream>>>(Wi, Wo, Ui, Uo, bi, bo, bui, buo,
                                               W0, Wl, bias);
  // 2. aggregate with h0 = node_reps (also fills loop-invariant edge halves)
  agg_kernel<true><<<MR, 256, 0, stream>>>(node_reps, in_idx, in_mask, out_idx,
                                           out_mask, in_edges, out_edges,
                                           edge_emb, X);
  // 3. z_base = X(K=1024) @ W0 + bias   (all loop-invariant terms)
  gemm_kernel<1024, 0, false><<<512, 256, 0, stream>>>(X, W0, bias, nullptr,
                                                       nullptr, zbase, nullptr,
                                                       nullptr);
  // 4. iter 0: Nh(h0) already in X cols [0,512). GEMM + fused LSTM, c=0.
  gemm_kernel<512, 1, true><<<512, 256, 0, stream>>>(X, Wl, nullptr, zbase,
                                                     mask, reps0, hbuf, cbuf);
  // 5. re-aggregate with h1
  agg_kernel<false><<<MR, 256, 0, stream>>>(hbuf, in_idx, in_mask, out_idx,
                                            out_mask, nullptr, nullptr, nullptr,
                                            X);
  // 6. iter 1: GEMM + fused LSTM
  gemm_kernel<512, 1, false><<<512, 256, 0, stream>>>(X, Wl, nullptr, zbase,
                                                      mask, reps1, hbuf, cbuf);
}

// Round 2
// 151.178 us; speedup vs baseline: 3.2653x; 3.2653x over previous
//
#include <hip/hip_runtime.h>
#include <math.h>

// (B,N,K,D,V,L) = (16,512,16,256,64,2)
#define Kn 16
#define Dd 256
#define NC 1024
#define MR 8192

typedef _Float16 h8 __attribute__((ext_vector_type(8)));
typedef _Float16 h4 __attribute__((ext_vector_type(4)));
typedef float f4 __attribute__((ext_vector_type(4)));

__device__ __forceinline__ void gload16(_Float16* lds, const _Float16* g) {
  __builtin_amdgcn_global_load_lds(
      (const __attribute__((address_space(1))) void*)g,
      (__attribute__((address_space(3))) void*)lds, 16, 0, 0);
}

// ---------------------------------------------------------------------------
// Weight prep: fold + gate-permute + fragmentize to fp16.
//   col' = 64*(d>>4) + 16*g + (d&15); orig col c = g*256 + d.
//   Fragment storage: Wf[kt][nt][lane][j], k = kt*32 + (lane>>4)*8 + j,
//   col' = nt*16 + (lane&15).
//   W0 rows: [Wi_top; Wo_top; Wi_bot+Ui_bot; Wo_bot+Uo_bot]  (K=1024)
//   Wl rows: [Ui_top; Uo_top]                                 (K=512)
//   biasq[d*4+g] = bi+bo+bui+buo at c.
// ---------------------------------------------------------------------------
__global__ void prep_kernel(const float* __restrict__ Wi, const float* __restrict__ Wo,
                            const float* __restrict__ Ui, const float* __restrict__ Uo,
                            const float* __restrict__ bi, const float* __restrict__ bo,
                            const float* __restrict__ bui, const float* __restrict__ buo,
                            _Float16* __restrict__ W0f, _Float16* __restrict__ Wlf,
                            float* __restrict__ biasq) {
  const int NW0 = 1024 * 1024, NWL = 512 * 1024;
  const int total = NW0 + NWL + 1024;
  for (int idx = blockIdx.x * blockDim.x + threadIdx.x; idx < total;
       idx += gridDim.x * blockDim.x) {
    if (idx < NW0 + NWL) {
      const bool isW0 = idx < NW0;
      const int j0 = isW0 ? idx : idx - NW0;
      const int j = j0 & 7, l = (j0 >> 3) & 63, nt = (j0 >> 9) & 63, kt = j0 >> 15;
      const int k = kt * 32 + ((l >> 4) << 3) + j;
      const int cp = nt * 16 + (l & 15);
      const int g = (cp >> 4) & 3;
      const int d = ((cp >> 6) << 4) + (cp & 15);
      const int c = g * 256 + d;
      float v;
      if (isW0) {
        if (k < 256)      v = Wi[k * NC + c];
        else if (k < 512) v = Wo[(k - 256) * NC + c];
        else if (k < 768) v = Wi[(k - 256) * NC + c] + Ui[(k - 256) * NC + c];
        else              v = Wo[(k - 512) * NC + c] + Uo[(k - 512) * NC + c];
        W0f[j0] = (_Float16)v;
      } else {
        const float v2 = (k < 256) ? Ui[k * NC + c] : Uo[(k - 256) * NC + c];
        Wlf[j0] = (_Float16)v2;
      }
    } else {
      const int cq = idx - NW0 - NWL;  // d*4+g
      const int d = cq >> 2, g = cq & 3;
      const int c = g * 256 + d;
      biasq[cq] = bi[c] + bo[c] + bui[c] + buo[c];
    }
  }
}

// ---------------------------------------------------------------------------
// Aggregation -> X fp16 row-major [8192][1024].
//   EDGES: 128 thr/row: t<32 Nh_in, <64 Nh_out, <96 E_in, <128 E_out.
//   !EDGES: 64 thr/row: Nh_in, Nh_out only (cols [0,512)).
//   Each thread: 8 consecutive cols, fp32 accumulate, 16B fp16 store.
// ---------------------------------------------------------------------------
template <bool EDGES>
__global__ __launch_bounds__(EDGES ? 128 : 64) void agg_kernel(
    const float* __restrict__ h,
    const int* __restrict__ iidx, const float* __restrict__ im,
    const int* __restrict__ oidx, const float* __restrict__ om,
    const int* __restrict__ ie, const int* __restrict__ oe,
    const float* __restrict__ emb,
    _Float16* __restrict__ X) {
  const int row = blockIdx.x;
  const int t = threadIdx.x;
  const int base = row * Kn;
  const int hb = row & ~511;

  __shared__ int sii[Kn], soi[Kn], sie[Kn], soe[Kn];
  __shared__ float sim[Kn], som[Kn];
  if (t < Kn) {
    sii[t] = iidx[base + t];
    soi[t] = oidx[base + t];
    sim[t] = im[base + t];
    som[t] = om[base + t];
    if (EDGES) {
      sie[t] = ie[base + t];
      soe[t] = oe[base + t];
    }
  }
  __syncthreads();

  const int sec = t >> 5;
  const int cb = (t & 31) * 8;
  const int* nidx = (sec == 0) ? sii : (sec == 1) ? soi : (sec == 2) ? sie : soe;
  const float* nm = (sec & 1) ? som : sim;
  const float* basep = (sec < 2) ? (h + (size_t)hb * Dd) : emb;

  f4 A0 = {0.f, 0.f, 0.f, 0.f}, A1 = {0.f, 0.f, 0.f, 0.f};
#pragma unroll
  for (int k = 0; k < Kn; k++) {
    const int nb = nidx[k];
    const float m = nm[k];
    const float* p = basep + (size_t)nb * Dd + cb;
    const f4 v0 = *(const f4*)p;
    const f4 v1 = *(const f4*)(p + 4);
    A0 += m * v0;
    A1 += m * v1;
  }
  h8 o;
#pragma unroll
  for (int j = 0; j < 4; j++) {
    o[j] = (_Float16)A0[j];
    o[j + 4] = (_Float16)A1[j];
  }
  *(h8*)&X[(size_t)row * NC + t * 8] = o;
}

// ---------------------------------------------------------------------------
// MFMA GEMM: C = A(8192 x 32*KTILES, lda=1024 fp16) @ W(fragment layout)
// 128x128 tile, 4 waves (2x2), 16x16x32 f16 MFMA, 4x4 frags/wave.
//   MODE 0: zq_out[row][d][g] = C + biasq          (fp16 gate-quads)
//   MODE 1: fused LSTM epilogue using zq gate-quads; FIRST => c_old = 0.
// ---------------------------------------------------------------------------
template <int KTILES, int MODE, bool FIRST>
__global__ __launch_bounds__(256) void mfma_gemm(
    const _Float16* __restrict__ A, const _Float16* __restrict__ Wf,
    const float* __restrict__ biasq, const _Float16* __restrict__ zq,
    const float* __restrict__ mask,
    _Float16* __restrict__ zq_out, float* __restrict__ reps,
    float* __restrict__ hbuf, float* __restrict__ cbuf) {
  __shared__ __align__(16) _Float16 Alds[8 * 512];
  __shared__ __align__(16) _Float16 Blds[8 * 512];

  // XCD-aware swizzle: 8 consecutive-bn blocks (sharing an A panel) per XCD.
  const int wg = (blockIdx.x & 7) * 64 + (blockIdx.x >> 3);
  const int bm = wg >> 3, bn = wg & 7;
  const int tid = threadIdx.x, lane = tid & 63, wid = tid >> 6;
  const int wr = wid >> 1, wc = wid & 1;
  const int lr = lane & 15, lg = lane >> 4;

  f4 acc[4][4] = {};

  const _Float16* srcA0 = A + (size_t)(bm * 128 + 2 * wid * 16 + lr) * NC + lg * 8;
  const _Float16* srcB0 = Wf + ((size_t)bn * 8 + 2 * wid) * 512 + lane * 8;
  _Float16* ldsA = &Alds[2 * wid * 512];
  _Float16* ldsB = &Blds[2 * wid * 512];

  for (int kt = 0; kt < KTILES; kt++) {
    const _Float16* sa = srcA0 + kt * 32;
    const _Float16* sb = srcB0 + (size_t)kt * 32768;
    gload16(ldsA, sa);
    gload16(ldsA + 512, sa + 16 * NC);
    gload16(ldsB, sb);
    gload16(ldsB + 512, sb + 512);
    __syncthreads();  // drains vmcnt(0): staged data visible

    h8 a[4], b[4];
#pragma unroll
    for (int m = 0; m < 4; m++) a[m] = *(const h8*)&Alds[(wr * 4 + m) * 512 + lane * 8];
#pragma unroll
    for (int n = 0; n < 4; n++) b[n] = *(const h8*)&Blds[(wc * 4 + n) * 512 + lane * 8];
#pragma unroll
    for (int m = 0; m < 4; m++)
#pragma unroll
      for (int n = 0; n < 4; n++)
        acc[m][n] = __builtin_amdgcn_mfma_f32_16x16x32_f16(a[m], b[n], acc[m][n], 0, 0, 0);
    __syncthreads();  // before overwriting LDS
  }

  // n-fragment index == gate index g; lane lr picks output dim.
  const int d = (bn * 2 + wc) * 16 + lr;
  const int row0 = bm * 128 + wr * 64;

  if (MODE == 0) {
    const f4 bq = *(const f4*)&biasq[d * 4];
#pragma unroll
    for (int i = 0; i < 4; i++) {
#pragma unroll
      for (int r = 0; r < 4; r++) {
        const int row = row0 + i * 16 + lg * 4 + r;
        h4 o;
        o[0] = (_Float16)(acc[i][0][r] + bq.x);
        o[1] = (_Float16)(acc[i][1][r] + bq.y);
        o[2] = (_Float16)(acc[i][2][r] + bq.z);
        o[3] = (_Float16)(acc[i][3][r] + bq.w);
        *(h4*)&zq_out[((size_t)row * Dd + d) * 4] = o;
      }
    }
  } else {
#pragma unroll
    for (int i = 0; i < 4; i++) {
#pragma unroll
      for (int r = 0; r < 4; r++) {
        const int row = row0 + i * 16 + lg * 4 + r;
        const size_t off = (size_t)row * Dd + d;
        const h4 zb = *(const h4*)&zq[off * 4];
        const float zi = acc[i][0][r] + (float)zb[0];
        const float zf = acc[i][1][r] + (float)zb[1];
        const float zo = acc[i][2][r] + (float)zb[2];
        const float zc = acc[i][3][r] + (float)zb[3];
        const float ig = 1.f / (1.f + expf(-zi));
        const float fg = 1.f / (1.f + expf(-zf));
        const float og = 1.f / (1.f + expf(-zo));
        const float ci = tanhf(zc);
        const float cold = FIRST ? 0.f : cbuf[off];
        const float cn = fg * cold + ig * ci;
        const float hn = og * tanhf(cn);
        const float mk = mask[row];
        cbuf[off] = cn * mk;
        const float hm = hn * mk;
        hbuf[off] = hm;
        reps[off] = hm;
      }
    }
  }
}

// ---------------------------------------------------------------------------
extern "C" void kernel_launch(void* const* d_in, const int* in_sizes, int n_in,
                              void* d_out, int out_size, void* d_ws, size_t ws_size,
                              hipStream_t stream) {
  const float* node_reps = (const float*)d_in[0];
  const float* mask      = (const float*)d_in[1];
  const int*   in_idx    = (const int*)d_in[2];
  const int*   in_edges  = (const int*)d_in[3];
  const float* in_mask   = (const float*)d_in[4];
  const int*   out_idx   = (const int*)d_in[5];
  const int*   out_edges = (const int*)d_in[6];
  const float* out_mask  = (const float*)d_in[7];
  const float* edge_emb  = (const float*)d_in[8];
  const float* Wi  = (const float*)d_in[9];
  const float* Wo  = (const float*)d_in[10];
  const float* Ui  = (const float*)d_in[11];
  const float* Uo  = (const float*)d_in[12];
  const float* bi  = (const float*)d_in[13];
  const float* bo  = (const float*)d_in[14];
  const float* bui = (const float*)d_in[15];
  const float* buo = (const float*)d_in[16];

  float* out = (float*)d_out;
  const size_t MD = (size_t)MR * Dd;
  float* reps0 = out;
  float* reps1 = out + MD;
  float* hbuf  = out + 2 * MD;
  float* cbuf  = out + 3 * MD;

  _Float16* X    = (_Float16*)d_ws;                 // 8192*1024 fp16 (16 MB)
  _Float16* zq   = X + (size_t)MR * NC;             // 8192*1024 fp16 (16 MB)
  _Float16* W0f  = zq + (size_t)MR * NC;            // 1024*1024 fp16 (2 MB)
  _Float16* Wlf  = W0f + 1024 * 1024;               // 512*1024 fp16 (1 MB)
  float*    biasq = (float*)(Wlf + 512 * 1024);     // 1024 f32

  // 1. fold + permute + fragmentize weights (fp16)
  prep_kernel<<<128, 256, 0, stream>>>(Wi, Wo, Ui, Uo, bi, bo, bui, buo,
                                       W0f, Wlf, biasq);
  // 2. aggregate with h0 = node_reps (fills all 1024 cols incl. edge halves)
  agg_kernel<true><<<MR, 128, 0, stream>>>(node_reps, in_idx, in_mask, out_idx,
                                           out_mask, in_edges, out_edges,
                                           edge_emb, X);
  // 3. zbase = X(K=1024) @ W0 + bias  -> fp16 gate-quads
  mfma_gemm<32, 0, false><<<512, 256, 0, stream>>>(X, W0f, biasq, nullptr,
                                                   nullptr, zq, nullptr,
                                                   nullptr, nullptr);
  // 4. iter 0: X[:, :512] @ Wl + zbase -> fused LSTM (c=0)
  mfma_gemm<16, 1, true><<<512, 256, 0, stream>>>(X, Wlf, nullptr, zq, mask,
                                                  nullptr, reps0, hbuf, cbuf);
  // 5. re-aggregate with h1 (overwrites X cols [0,512) only)
  agg_kernel<false><<<MR, 64, 0, stream>>>(hbuf, in_idx, in_mask, out_idx,
                                           out_mask, nullptr, nullptr, nullptr,
                                           X);
  // 6. iter 1: GEMM + fused LSTM
  mfma_gemm<16, 1, false><<<512, 256, 0, stream>>>(X, Wlf, nullptr, zq, mask,
                                                   nullptr, reps1, hbuf, cbuf);
}

// Round 3
// 114.120 us; speedup vs baseline: 4.3255x; 1.3247x over previous
//
#include <hip/hip_runtime.h>
#include <math.h>

// (B,N,K,D,V,L) = (16,512,16,256,64,2)
#define Kn 16
#define Dd 256
#define NC 1024
#define MR 8192

typedef _Float16 h8 __attribute__((ext_vector_type(8)));
typedef _Float16 h4 __attribute__((ext_vector_type(4)));
typedef float f4 __attribute__((ext_vector_type(4)));

__device__ __forceinline__ void gload16(_Float16* lds, const _Float16* g) {
  __builtin_amdgcn_global_load_lds(
      (const __attribute__((address_space(1))) void*)g,
      (__attribute__((address_space(3))) void*)lds, 16, 0, 0);
}

__device__ __forceinline__ float fsigm(float x) { return 1.f / (1.f + __expf(-x)); }
__device__ __forceinline__ float ftanh(float x) { return 2.f / (1.f + __expf(-2.f * x)) - 1.f; }

// ---------------------------------------------------------------------------
// Block 0..8191: aggregation with h0=node_reps (all 4 X sections).
// Block 8192+ : weight fold/permute/fragmentize (grid-stride).
//   X cols: [Nh_in | Nh_out | E_in | E_out]; gate-permuted col' = 64*(d>>4)+16*g+(d&15)
//   Fragment: Wf[kt][nt][lane][j], k = kt*32+(lane>>4)*8+j, col' = nt*16+(lane&15)
// ---------------------------------------------------------------------------
__global__ __launch_bounds__(128) void prep_agg_kernel(
    const float* __restrict__ node_reps,
    const int* __restrict__ iidx, const float* __restrict__ im,
    const int* __restrict__ oidx, const float* __restrict__ om,
    const int* __restrict__ ie, const int* __restrict__ oe,
    const float* __restrict__ emb,
    const float* __restrict__ Wi, const float* __restrict__ Wo,
    const float* __restrict__ Ui, const float* __restrict__ Uo,
    const float* __restrict__ bi, const float* __restrict__ bo,
    const float* __restrict__ bui, const float* __restrict__ buo,
    _Float16* __restrict__ X, _Float16* __restrict__ W0f,
    _Float16* __restrict__ Wlf, float* __restrict__ biasq) {
  const int t = threadIdx.x;
  if (blockIdx.x < MR) {
    // XCD swizzle: XCD x -> rows [x*1024, x*1024+1024) = 2 batches (1 MB L2 set)
    const int row = (blockIdx.x & 7) * 1024 + (blockIdx.x >> 3);
    const int base = row * Kn;
    const int hb = row & ~511;
    __shared__ int sii[Kn], soi[Kn], sie[Kn], soe[Kn];
    __shared__ float sim[Kn], som[Kn];
    if (t < Kn) {
      sii[t] = iidx[base + t]; soi[t] = oidx[base + t];
      sim[t] = im[base + t];   som[t] = om[base + t];
      sie[t] = ie[base + t];   soe[t] = oe[base + t];
    }
    __syncthreads();
    const int sec = t >> 5;
    const int cb = (t & 31) * 8;
    const int* nidx = (sec == 0) ? sii : (sec == 1) ? soi : (sec == 2) ? sie : soe;
    const float* nm = (sec & 1) ? som : sim;
    const float* basep = (sec < 2) ? (node_reps + (size_t)hb * Dd) : emb;
    f4 A0 = {0.f, 0.f, 0.f, 0.f}, A1 = {0.f, 0.f, 0.f, 0.f};
#pragma unroll
    for (int k = 0; k < Kn; k++) {
      const float m = nm[k];
      const float* p = basep + (size_t)nidx[k] * Dd + cb;
      A0 += m * *(const f4*)p;
      A1 += m * *(const f4*)(p + 4);
    }
    h8 o;
#pragma unroll
    for (int j = 0; j < 4; j++) { o[j] = (_Float16)A0[j]; o[j + 4] = (_Float16)A1[j]; }
    *(h8*)&X[(size_t)row * NC + sec * 256 + cb] = o;
  } else {
    const int NW0 = 1024 * 1024, NWL = 512 * 1024;
    const int total = NW0 + NWL + 1024;
    for (int idx = (blockIdx.x - MR) * 128 + t; idx < total; idx += 256 * 128) {
      if (idx < NW0 + NWL) {
        const bool isW0 = idx < NW0;
        const int j0 = isW0 ? idx : idx - NW0;
        const int j = j0 & 7, l = (j0 >> 3) & 63, nt = (j0 >> 9) & 63, kt = j0 >> 15;
        const int k = kt * 32 + ((l >> 4) << 3) + j;
        const int cp = nt * 16 + (l & 15);
        const int g = (cp >> 4) & 3;
        const int dd = ((cp >> 6) << 4) + (cp & 15);
        const int c = g * 256 + dd;
        if (isW0) {
          float v;
          if (k < 256)      v = Wi[k * NC + c];
          else if (k < 512) v = Wo[(k - 256) * NC + c];
          else if (k < 768) v = Wi[(k - 256) * NC + c] + Ui[(k - 256) * NC + c];
          else              v = Wo[(k - 512) * NC + c] + Uo[(k - 512) * NC + c];
          W0f[j0] = (_Float16)v;
        } else {
          Wlf[j0] = (_Float16)((k < 256) ? Ui[k * NC + c] : Uo[(k - 256) * NC + c]);
        }
      } else {
        const int cq = idx - NW0 - NWL;
        const int dd = cq >> 2, g = cq & 3;
        const int c = g * 256 + dd;
        biasq[cq] = bi[c] + bo[c] + bui[c] + buo[c];
      }
    }
  }
}

// ---------------------------------------------------------------------------
// Iter-1 aggregation from fp16 h copy -> X cols [0,512).
// ---------------------------------------------------------------------------
__global__ __launch_bounds__(64) void agg1_kernel(
    const _Float16* __restrict__ h16,
    const int* __restrict__ iidx, const float* __restrict__ im,
    const int* __restrict__ oidx, const float* __restrict__ om,
    _Float16* __restrict__ X) {
  const int t = threadIdx.x;
  const int row = (blockIdx.x & 7) * 1024 + (blockIdx.x >> 3);
  const int base = row * Kn;
  const int hb = row & ~511;
  __shared__ int sii[Kn], soi[Kn];
  __shared__ float sim[Kn], som[Kn];
  if (t < Kn) {
    sii[t] = iidx[base + t]; soi[t] = oidx[base + t];
    sim[t] = im[base + t];   som[t] = om[base + t];
  }
  __syncthreads();
  const int sec = t >> 5;  // 0: in, 1: out
  const int cb = (t & 31) * 8;
  const int* nidx = sec ? soi : sii;
  const float* nm = sec ? som : sim;
  const _Float16* hp = h16 + (size_t)hb * Dd + cb;
  f4 A0 = {0.f, 0.f, 0.f, 0.f}, A1 = {0.f, 0.f, 0.f, 0.f};
#pragma unroll
  for (int k = 0; k < Kn; k++) {
    const float m = nm[k];
    const h8 v = *(const h8*)(hp + (size_t)nidx[k] * Dd);
#pragma unroll
    for (int j = 0; j < 4; j++) {
      A0[j] += m * (float)v[j];
      A1[j] += m * (float)v[j + 4];
    }
  }
  h8 o;
#pragma unroll
  for (int j = 0; j < 4; j++) { o[j] = (_Float16)A0[j]; o[j + 4] = (_Float16)A1[j]; }
  *(h8*)&X[(size_t)row * NC + sec * 256 + cb] = o;
}

// ---------------------------------------------------------------------------
// Fused MFMA GEMM + LSTM. 128x128 tile, 4 waves (2x2), 16x16x32 f16 MFMA,
// double-buffered LDS (2-phase: issue next-tile gload_lds before current
// ds_read+MFMA; single barrier per K-step).
//   WITH_Z (iter 0): accZ = X@W0 (K=1024), accL = X[:,:512]@Wl; writes
//     zq = fp16(accZ+bias) gate-quads, then LSTM on (accZ+bias+accL), c_old=0;
//     writes reps0 (f32) + h16 (fp16 working copy) + cbuf.
//   !WITH_Z (iter 1): accL = X[:,:512]@Wl; z = zq + accL; LSTM with cbuf;
//     writes reps1 + hbuf + cbuf (all final outputs).
// ---------------------------------------------------------------------------
template <bool WITH_Z, bool FIRST>
__global__ __launch_bounds__(256) void fused_gemm(
    const _Float16* __restrict__ A, const _Float16* __restrict__ W0f,
    const _Float16* __restrict__ Wlf, const float* __restrict__ biasq,
    _Float16* __restrict__ zq, const float* __restrict__ mask,
    float* __restrict__ reps, float* __restrict__ hbuf,
    _Float16* __restrict__ h16, float* __restrict__ cbuf) {
  constexpr int KT = WITH_Z ? 32 : 16;
  constexpr int NB = WITH_Z ? 3 : 2;
  __shared__ __align__(16) _Float16 lds[2][NB * 4096];

  // XCD swizzle: XCD x gets bm in [x*8, x*8+8) x all bn (A-panel+B ~4MB L2)
  const int wg = (blockIdx.x & 7) * 64 + (blockIdx.x >> 3);
  const int bm = wg >> 3, bn = wg & 7;
  const int tid = threadIdx.x, lane = tid & 63, wid = tid >> 6;
  const int wr = wid >> 1, wc = wid & 1;
  const int lr = lane & 15, lg = lane >> 4;

  f4 accL[4][4] = {};
  f4 accZ[4][4] = {};

  const _Float16* srcA0 = A + (size_t)(bm * 128 + 2 * wid * 16 + lr) * NC + lg * 8;
  const _Float16* srcBl0 = Wlf + ((size_t)bn * 8 + 2 * wid) * 512 + lane * 8;
  const _Float16* srcB00 = W0f + ((size_t)bn * 8 + 2 * wid) * 512 + lane * 8;
  const int woff = 2 * wid * 512;

  auto stage = [&](int buf, int kt) {
    _Float16* base = lds[buf];
    const _Float16* sa = srcA0 + kt * 32;
    gload16(base + woff, sa);
    gload16(base + woff + 512, sa + 16 * NC);
    if (kt < 16) {
      const _Float16* sb = srcBl0 + (size_t)kt * 32768;
      gload16(base + 4096 + woff, sb);
      gload16(base + 4096 + woff + 512, sb + 512);
    }
    if (WITH_Z) {
      const _Float16* sb = srcB00 + (size_t)kt * 32768;
      gload16(base + 8192 + woff, sb);
      gload16(base + 8192 + woff + 512, sb + 512);
    }
  };

  stage(0, 0);
  __syncthreads();
  for (int kt = 0; kt < KT; kt++) {
    const int cur = kt & 1;
    if (kt + 1 < KT) stage(cur ^ 1, kt + 1);  // prefetch under compute
    const _Float16* base = lds[cur];
    h8 a[4];
#pragma unroll
    for (int m = 0; m < 4; m++) a[m] = *(const h8*)&base[(wr * 4 + m) * 512 + lane * 8];
    if (kt < 16) {
      h8 b[4];
#pragma unroll
      for (int n = 0; n < 4; n++) b[n] = *(const h8*)&base[4096 + (wc * 4 + n) * 512 + lane * 8];
#pragma unroll
      for (int m = 0; m < 4; m++)
#pragma unroll
        for (int n = 0; n < 4; n++)
          accL[m][n] = __builtin_amdgcn_mfma_f32_16x16x32_f16(a[m], b[n], accL[m][n], 0, 0, 0);
    }
    if (WITH_Z) {
      h8 b[4];
#pragma unroll
      for (int n = 0; n < 4; n++) b[n] = *(const h8*)&base[8192 + (wc * 4 + n) * 512 + lane * 8];
#pragma unroll
      for (int m = 0; m < 4; m++)
#pragma unroll
        for (int n = 0; n < 4; n++)
          accZ[m][n] = __builtin_amdgcn_mfma_f32_16x16x32_f16(a[m], b[n], accZ[m][n], 0, 0, 0);
    }
    __syncthreads();  // compiler emits vmcnt(0)+lgkmcnt(0) drain here
  }

  // epilogue: n-fragment index == gate g; lane lr picks output dim
  const int d = (bn * 2 + wc) * 16 + lr;
  const int row0 = bm * 128 + wr * 64;
  f4 bq = {0.f, 0.f, 0.f, 0.f};
  if (WITH_Z) bq = *(const f4*)&biasq[d * 4];
#pragma unroll
  for (int i = 0; i < 4; i++) {
#pragma unroll
    for (int r = 0; r < 4; r++) {
      const int row = row0 + i * 16 + lg * 4 + r;
      const size_t off = (size_t)row * Dd + d;
      float zi, zf, zo, zc;
      if (WITH_Z) {
        const float z0 = accZ[i][0][r] + bq.x;
        const float z1 = accZ[i][1][r] + bq.y;
        const float z2 = accZ[i][2][r] + bq.z;
        const float z3 = accZ[i][3][r] + bq.w;
        h4 oz;
        oz[0] = (_Float16)z0; oz[1] = (_Float16)z1;
        oz[2] = (_Float16)z2; oz[3] = (_Float16)z3;
        *(h4*)&zq[off * 4] = oz;
        zi = z0 + accL[i][0][r]; zf = z1 + accL[i][1][r];
        zo = z2 + accL[i][2][r]; zc = z3 + accL[i][3][r];
      } else {
        const h4 zb = *(const h4*)&zq[off * 4];
        zi = (float)zb[0] + accL[i][0][r]; zf = (float)zb[1] + accL[i][1][r];
        zo = (float)zb[2] + accL[i][2][r]; zc = (float)zb[3] + accL[i][3][r];
      }
      const float ig = fsigm(zi), fg = fsigm(zf), og = fsigm(zo), ci = ftanh(zc);
      const float cold = FIRST ? 0.f : cbuf[off];
      const float cn = fg * cold + ig * ci;
      const float hn = og * ftanh(cn);
      const float mk = mask[row];
      cbuf[off] = cn * mk;
      const float hm = hn * mk;
      reps[off] = hm;
      if (FIRST) h16[off] = (_Float16)hm;   // fp16 working h for iter-1 gather
      else       hbuf[off] = hm;            // final h output
    }
  }
}

// ---------------------------------------------------------------------------
extern "C" void kernel_launch(void* const* d_in, const int* in_sizes, int n_in,
                              void* d_out, int out_size, void* d_ws, size_t ws_size,
                              hipStream_t stream) {
  const float* node_reps = (const float*)d_in[0];
  const float* mask      = (const float*)d_in[1];
  const int*   in_idx    = (const int*)d_in[2];
  const int*   in_edges  = (const int*)d_in[3];
  const float* in_mask   = (const float*)d_in[4];
  const int*   out_idx   = (const int*)d_in[5];
  const int*   out_edges = (const int*)d_in[6];
  const float* out_mask  = (const float*)d_in[7];
  const float* edge_emb  = (const float*)d_in[8];
  const float* Wi  = (const float*)d_in[9];
  const float* Wo  = (const float*)d_in[10];
  const float* Ui  = (const float*)d_in[11];
  const float* Uo  = (const float*)d_in[12];
  const float* bi  = (const float*)d_in[13];
  const float* bo  = (const float*)d_in[14];
  const float* bui = (const float*)d_in[15];
  const float* buo = (const float*)d_in[16];

  float* out = (float*)d_out;
  const size_t MD = (size_t)MR * Dd;
  float* reps0 = out;
  float* reps1 = out + MD;
  float* hbuf  = out + 2 * MD;
  float* cbuf  = out + 3 * MD;

  _Float16* X    = (_Float16*)d_ws;                 // 16 MB
  _Float16* zq   = X + (size_t)MR * NC;             // 16 MB
  _Float16* W0f  = zq + (size_t)MR * NC;            // 2 MB
  _Float16* Wlf  = W0f + 1024 * 1024;               // 1 MB
  _Float16* h16  = Wlf + 512 * 1024;                // 4 MB
  float*    biasq = (float*)(h16 + (size_t)MR * Dd);

  // 1. aggregate(h0) || weight prep
  prep_agg_kernel<<<MR + 256, 128, 0, stream>>>(
      node_reps, in_idx, in_mask, out_idx, out_mask, in_edges, out_edges,
      edge_emb, Wi, Wo, Ui, Uo, bi, bo, bui, buo, X, W0f, Wlf, biasq);
  // 2. dual-acc GEMM: zbase (K=1024) + iter-0 loop GEMM (K=512) + LSTM0
  fused_gemm<true, true><<<512, 256, 0, stream>>>(
      X, W0f, Wlf, biasq, zq, mask, reps0, nullptr, h16, cbuf);
  // 3. re-aggregate from fp16 h
  agg1_kernel<<<MR, 64, 0, stream>>>(h16, in_idx, in_mask, out_idx, out_mask, X);
  // 4. iter-1 GEMM (K=512) + LSTM1 -> final outputs
  fused_gemm<false, false><<<512, 256, 0, stream>>>(
      X, W0f, Wlf, biasq, zq, mask, reps1, hbuf, h16, cbuf);
}

// Round 4
// 113.545 us; speedup vs baseline: 4.3475x; 1.0051x over previous
//
#include <hip/hip_runtime.h>
#include <math.h>

// (B,N,K,D,V,L) = (16,512,16,256,64,2)
#define Kn 16
#define Dd 256
#define NC 1024
#define MR 8192

typedef _Float16 h8 __attribute__((ext_vector_type(8)));
typedef _Float16 h4 __attribute__((ext_vector_type(4)));
typedef float f4 __attribute__((ext_vector_type(4)));

__device__ __forceinline__ void gload16(_Float16* lds, const _Float16* g) {
  __builtin_amdgcn_global_load_lds(
      (const __attribute__((address_space(1))) void*)g,
      (__attribute__((address_space(3))) void*)lds, 16, 0, 0);
}

__device__ __forceinline__ float fsigm(float x) { return 1.f / (1.f + __expf(-x)); }
__device__ __forceinline__ float ftanh(float x) { return 2.f / (1.f + __expf(-2.f * x)) - 1.f; }

// ---------------------------------------------------------------------------
// Block 0..8191: aggregation with h0=node_reps (all 4 X sections), f32 gather
//   with register-batched loads (8 in flight) to beat L2 latency.
// Block 8192+ : weight fold/permute/fragmentize (grid-stride).
// ---------------------------------------------------------------------------
__global__ __launch_bounds__(128, 3) void prep_agg_kernel(
    const float* __restrict__ node_reps,
    const int* __restrict__ iidx, const float* __restrict__ im,
    const int* __restrict__ oidx, const float* __restrict__ om,
    const int* __restrict__ ie, const int* __restrict__ oe,
    const float* __restrict__ emb,
    const float* __restrict__ Wi, const float* __restrict__ Wo,
    const float* __restrict__ Ui, const float* __restrict__ Uo,
    const float* __restrict__ bi, const float* __restrict__ bo,
    const float* __restrict__ bui, const float* __restrict__ buo,
    _Float16* __restrict__ X, _Float16* __restrict__ W0f,
    _Float16* __restrict__ Wlf, float* __restrict__ biasq) {
  const int t = threadIdx.x;
  if (blockIdx.x < MR) {
    // XCD swizzle: XCD x -> rows [x*1024, x*1024+1024) = 2 batches (1 MB L2 set)
    const int row = (blockIdx.x & 7) * 1024 + (blockIdx.x >> 3);
    const int base = row * Kn;
    const int hb = row & ~511;
    __shared__ int sidx[4 * Kn];
    __shared__ float smask[2 * Kn];
    if (t < Kn) {
      sidx[t] = iidx[base + t];
      sidx[Kn + t] = oidx[base + t];
      sidx[2 * Kn + t] = ie[base + t];
      sidx[3 * Kn + t] = oe[base + t];
      smask[t] = im[base + t];
      smask[Kn + t] = om[base + t];
    }
    __syncthreads();
    const int sec = t >> 5;
    const int cb = (t & 31) * 8;
    const int* nidx = &sidx[sec * Kn];
    const float* nm = &smask[(sec & 1) * Kn];
    const float* basep = (sec < 2) ? (node_reps + (size_t)hb * Dd) : emb;

    int idxr[Kn];
    float mr[Kn];
#pragma unroll
    for (int k = 0; k < Kn; k++) { idxr[k] = nidx[k]; mr[k] = nm[k]; }

    f4 A0 = {0.f, 0.f, 0.f, 0.f}, A1 = {0.f, 0.f, 0.f, 0.f};
#pragma unroll
    for (int kb = 0; kb < 2; kb++) {
      f4 w0[8], w1[8];
#pragma unroll
      for (int k = 0; k < 8; k++) {  // 16 loads issued before any use
        const float* p = basep + (size_t)idxr[kb * 8 + k] * Dd + cb;
        w0[k] = *(const f4*)p;
        w1[k] = *(const f4*)(p + 4);
      }
#pragma unroll
      for (int k = 0; k < 8; k++) {
        const float m = mr[kb * 8 + k];
        A0 += m * w0[k];
        A1 += m * w1[k];
      }
    }
    h8 o;
#pragma unroll
    for (int j = 0; j < 4; j++) { o[j] = (_Float16)A0[j]; o[j + 4] = (_Float16)A1[j]; }
    *(h8*)&X[(size_t)row * NC + sec * 256 + cb] = o;
  } else {
    const int NW0 = 1024 * 1024, NWL = 512 * 1024;
    const int total = NW0 + NWL + 1024;
    for (int idx = (blockIdx.x - MR) * 128 + t; idx < total; idx += 256 * 128) {
      if (idx < NW0 + NWL) {
        const bool isW0 = idx < NW0;
        const int j0 = isW0 ? idx : idx - NW0;
        const int j = j0 & 7, l = (j0 >> 3) & 63, nt = (j0 >> 9) & 63, kt = j0 >> 15;
        const int k = kt * 32 + ((l >> 4) << 3) + j;
        const int cp = nt * 16 + (l & 15);
        const int g = (cp >> 4) & 3;
        const int dd = ((cp >> 6) << 4) + (cp & 15);
        const int c = g * 256 + dd;
        if (isW0) {
          float v;
          if (k < 256)      v = Wi[k * NC + c];
          else if (k < 512) v = Wo[(k - 256) * NC + c];
          else if (k < 768) v = Wi[(k - 256) * NC + c] + Ui[(k - 256) * NC + c];
          else              v = Wo[(k - 512) * NC + c] + Uo[(k - 512) * NC + c];
          W0f[j0] = (_Float16)v;
        } else {
          Wlf[j0] = (_Float16)((k < 256) ? Ui[k * NC + c] : Uo[(k - 256) * NC + c]);
        }
      } else {
        const int cq = idx - NW0 - NWL;
        const int dd = cq >> 2, g = cq & 3;
        const int c = g * 256 + dd;
        biasq[cq] = bi[c] + bo[c] + bui[c] + buo[c];
      }
    }
  }
}

// ---------------------------------------------------------------------------
// Iter-1 aggregation from fp16 h copy -> X cols [0,512).
// Register-batched 16B gathers.
// ---------------------------------------------------------------------------
__global__ __launch_bounds__(64, 4) void agg1_kernel(
    const _Float16* __restrict__ h16,
    const int* __restrict__ iidx, const float* __restrict__ im,
    const int* __restrict__ oidx, const float* __restrict__ om,
    _Float16* __restrict__ X) {
  const int t = threadIdx.x;
  const int row = (blockIdx.x & 7) * 1024 + (blockIdx.x >> 3);
  const int base = row * Kn;
  const int hb = row & ~511;
  __shared__ int sidx[2 * Kn];
  __shared__ float smask[2 * Kn];
  if (t < Kn) {
    sidx[t] = iidx[base + t];
    sidx[Kn + t] = oidx[base + t];
    smask[t] = im[base + t];
    smask[Kn + t] = om[base + t];
  }
  __syncthreads();
  const int sec = t >> 5;  // 0: in, 1: out
  const int cb = (t & 31) * 8;
  const int* nidx = &sidx[sec * Kn];
  const float* nm = &smask[sec * Kn];
  const _Float16* hp = h16 + (size_t)hb * Dd + cb;

  int idxr[Kn];
  float mr[Kn];
#pragma unroll
  for (int k = 0; k < Kn; k++) { idxr[k] = nidx[k]; mr[k] = nm[k]; }

  f4 A0 = {0.f, 0.f, 0.f, 0.f}, A1 = {0.f, 0.f, 0.f, 0.f};
#pragma unroll
  for (int kb = 0; kb < 2; kb++) {
    h8 w[8];
#pragma unroll
    for (int k = 0; k < 8; k++)  // 8 x 16B loads in flight
      w[k] = *(const h8*)(hp + (size_t)idxr[kb * 8 + k] * Dd);
#pragma unroll
    for (int k = 0; k < 8; k++) {
      const float m = mr[kb * 8 + k];
#pragma unroll
      for (int j = 0; j < 4; j++) {
        A0[j] += m * (float)w[k][j];
        A1[j] += m * (float)w[k][j + 4];
      }
    }
  }
  h8 o;
#pragma unroll
  for (int j = 0; j < 4; j++) { o[j] = (_Float16)A0[j]; o[j + 4] = (_Float16)A1[j]; }
  *(h8*)&X[(size_t)row * NC + sec * 256 + cb] = o;
}

// ---------------------------------------------------------------------------
// Fused MFMA GEMM + LSTM. 128x128 tile, 4 waves (2x2), 16x16x32 f16 MFMA,
// double-buffered LDS (2-phase). Unchanged from R3.
// ---------------------------------------------------------------------------
template <bool WITH_Z, bool FIRST>
__global__ __launch_bounds__(256) void fused_gemm(
    const _Float16* __restrict__ A, const _Float16* __restrict__ W0f,
    const _Float16* __restrict__ Wlf, const float* __restrict__ biasq,
    _Float16* __restrict__ zq, const float* __restrict__ mask,
    float* __restrict__ reps, float* __restrict__ hbuf,
    _Float16* __restrict__ h16, float* __restrict__ cbuf) {
  constexpr int KT = WITH_Z ? 32 : 16;
  constexpr int NB = WITH_Z ? 3 : 2;
  __shared__ __align__(16) _Float16 lds[2][NB * 4096];

  const int wg = (blockIdx.x & 7) * 64 + (blockIdx.x >> 3);
  const int bm = wg >> 3, bn = wg & 7;
  const int tid = threadIdx.x, lane = tid & 63, wid = tid >> 6;
  const int wr = wid >> 1, wc = wid & 1;
  const int lr = lane & 15, lg = lane >> 4;

  f4 accL[4][4] = {};
  f4 accZ[4][4] = {};

  const _Float16* srcA0 = A + (size_t)(bm * 128 + 2 * wid * 16 + lr) * NC + lg * 8;
  const _Float16* srcBl0 = Wlf + ((size_t)bn * 8 + 2 * wid) * 512 + lane * 8;
  const _Float16* srcB00 = W0f + ((size_t)bn * 8 + 2 * wid) * 512 + lane * 8;
  const int woff = 2 * wid * 512;

  auto stage = [&](int buf, int kt) {
    _Float16* base = lds[buf];
    const _Float16* sa = srcA0 + kt * 32;
    gload16(base + woff, sa);
    gload16(base + woff + 512, sa + 16 * NC);
    if (kt < 16) {
      const _Float16* sb = srcBl0 + (size_t)kt * 32768;
      gload16(base + 4096 + woff, sb);
      gload16(base + 4096 + woff + 512, sb + 512);
    }
    if (WITH_Z) {
      const _Float16* sb = srcB00 + (size_t)kt * 32768;
      gload16(base + 8192 + woff, sb);
      gload16(base + 8192 + woff + 512, sb + 512);
    }
  };

  stage(0, 0);
  __syncthreads();
  for (int kt = 0; kt < KT; kt++) {
    const int cur = kt & 1;
    if (kt + 1 < KT) stage(cur ^ 1, kt + 1);  // prefetch under compute
    const _Float16* base = lds[cur];
    h8 a[4];
#pragma unroll
    for (int m = 0; m < 4; m++) a[m] = *(const h8*)&base[(wr * 4 + m) * 512 + lane * 8];
    if (kt < 16) {
      h8 b[4];
#pragma unroll
      for (int n = 0; n < 4; n++) b[n] = *(const h8*)&base[4096 + (wc * 4 + n) * 512 + lane * 8];
#pragma unroll
      for (int m = 0; m < 4; m++)
#pragma unroll
        for (int n = 0; n < 4; n++)
          accL[m][n] = __builtin_amdgcn_mfma_f32_16x16x32_f16(a[m], b[n], accL[m][n], 0, 0, 0);
    }
    if (WITH_Z) {
      h8 b[4];
#pragma unroll
      for (int n = 0; n < 4; n++) b[n] = *(const h8*)&base[8192 + (wc * 4 + n) * 512 + lane * 8];
#pragma unroll
      for (int m = 0; m < 4; m++)
#pragma unroll
        for (int n = 0; n < 4; n++)
          accZ[m][n] = __builtin_amdgcn_mfma_f32_16x16x32_f16(a[m], b[n], accZ[m][n], 0, 0, 0);
    }
    __syncthreads();
  }

  const int d = (bn * 2 + wc) * 16 + lr;
  const int row0 = bm * 128 + wr * 64;
  f4 bq = {0.f, 0.f, 0.f, 0.f};
  if (WITH_Z) bq = *(const f4*)&biasq[d * 4];
#pragma unroll
  for (int i = 0; i < 4; i++) {
#pragma unroll
    for (int r = 0; r < 4; r++) {
      const int row = row0 + i * 16 + lg * 4 + r;
      const size_t off = (size_t)row * Dd + d;
      float zi, zf, zo, zc;
      if (WITH_Z) {
        const float z0 = accZ[i][0][r] + bq.x;
        const float z1 = accZ[i][1][r] + bq.y;
        const float z2 = accZ[i][2][r] + bq.z;
        const float z3 = accZ[i][3][r] + bq.w;
        h4 oz;
        oz[0] = (_Float16)z0; oz[1] = (_Float16)z1;
        oz[2] = (_Float16)z2; oz[3] = (_Float16)z3;
        *(h4*)&zq[off * 4] = oz;
        zi = z0 + accL[i][0][r]; zf = z1 + accL[i][1][r];
        zo = z2 + accL[i][2][r]; zc = z3 + accL[i][3][r];
      } else {
        const h4 zb = *(const h4*)&zq[off * 4];
        zi = (float)zb[0] + accL[i][0][r]; zf = (float)zb[1] + accL[i][1][r];
        zo = (float)zb[2] + accL[i][2][r]; zc = (float)zb[3] + accL[i][3][r];
      }
      const float ig = fsigm(zi), fg = fsigm(zf), og = fsigm(zo), ci = ftanh(zc);
      const float cold = FIRST ? 0.f : cbuf[off];
      const float cn = fg * cold + ig * ci;
      const float hn = og * ftanh(cn);
      const float mk = mask[row];
      cbuf[off] = cn * mk;
      const float hm = hn * mk;
      reps[off] = hm;
      if (FIRST) h16[off] = (_Float16)hm;
      else       hbuf[off] = hm;
    }
  }
}

// ---------------------------------------------------------------------------
extern "C" void kernel_launch(void* const* d_in, const int* in_sizes, int n_in,
                              void* d_out, int out_size, void* d_ws, size_t ws_size,
                              hipStream_t stream) {
  const float* node_reps = (const float*)d_in[0];
  const float* mask      = (const float*)d_in[1];
  const int*   in_idx    = (const int*)d_in[2];
  const int*   in_edges  = (const int*)d_in[3];
  const float* in_mask   = (const float*)d_in[4];
  const int*   out_idx   = (const int*)d_in[5];
  const int*   out_edges = (const int*)d_in[6];
  const float* out_mask  = (const float*)d_in[7];
  const float* edge_emb  = (const float*)d_in[8];
  const float* Wi  = (const float*)d_in[9];
  const float* Wo  = (const float*)d_in[10];
  const float* Ui  = (const float*)d_in[11];
  const float* Uo  = (const float*)d_in[12];
  const float* bi  = (const float*)d_in[13];
  const float* bo  = (const float*)d_in[14];
  const float* bui = (const float*)d_in[15];
  const float* buo = (const float*)d_in[16];

  float* out = (float*)d_out;
  const size_t MD = (size_t)MR * Dd;
  float* reps0 = out;
  float* reps1 = out + MD;
  float* hbuf  = out + 2 * MD;
  float* cbuf  = out + 3 * MD;

  _Float16* X    = (_Float16*)d_ws;                 // 16 MB
  _Float16* zq   = X + (size_t)MR * NC;             // 16 MB
  _Float16* W0f  = zq + (size_t)MR * NC;            // 2 MB
  _Float16* Wlf  = W0f + 1024 * 1024;               // 1 MB
  _Float16* h16  = Wlf + 512 * 1024;                // 4 MB
  float*    biasq = (float*)(h16 + (size_t)MR * Dd);

  // 1. aggregate(h0) || weight prep
  prep_agg_kernel<<<MR + 256, 128, 0, stream>>>(
      node_reps, in_idx, in_mask, out_idx, out_mask, in_edges, out_edges,
      edge_emb, Wi, Wo, Ui, Uo, bi, bo, bui, buo, X, W0f, Wlf, biasq);
  // 2. dual-acc GEMM: zbase (K=1024) + iter-0 loop GEMM (K=512) + LSTM0
  fused_gemm<true, true><<<512, 256, 0, stream>>>(
      X, W0f, Wlf, biasq, zq, mask, reps0, nullptr, h16, cbuf);
  // 3. re-aggregate from fp16 h
  agg1_kernel<<<MR, 64, 0, stream>>>(h16, in_idx, in_mask, out_idx, out_mask, X);
  // 4. iter-1 GEMM (K=512) + LSTM1 -> final outputs
  fused_gemm<false, false><<<512, 256, 0, stream>>>(
      X, W0f, Wlf, biasq, zq, mask, reps1, hbuf, h16, cbuf);
}